// Round 1
// baseline (964.122 us; speedup 1.0000x reference)
//
#include <hip/hip_runtime.h>

#define NT 2000
#define NS 2048
#define NH 16
#define U 16

// v + (v shifted right by N lanes within the 16-lane DPP row, 0-filled).
// row_shr:N ctrl = 0x110|N. old=0 + bound_ctrl=false -> invalid lanes read 0.
#define DPP_SHR_ADD(v, ctrl) \
    ((v) + __int_as_float(__builtin_amdgcn_update_dpp( \
        0, __float_as_int(v), (ctrl), 0xf, 0xf, false)))

// One thread per (site, head) chain; nh = low 4 bits so Fh/Hh/Gh stores
// (layout [t][s][nh]) are lane-coalesced. Only ~0.5 waves/SIMD can exist
// (32768 chains total) -> zero TLP; all latency hiding must be ILP.
// Q reduction over the 16 heads is done with DPP row_shr prefix adds
// (pure VALU, no lgkmcnt) instead of ds_bpermute shuffles; lane nh==15
// holds the row sum. Loads are prefetched one 16-step group ahead
// (~1200+ cyc in flight > HBM latency). All output stores nontemporal
// (write-once streaming, 803 MB).
__global__ __launch_bounds__(64) void waternet_kernel(
    const float* __restrict__ P, const float* __restrict__ T,
    const float* __restrict__ E,
    const float* __restrict__ w_o, const float* __restrict__ wF,
    const float* __restrict__ wG, const float* __restrict__ wl,
    const float* __restrict__ we, const float* __restrict__ wk,
    const float* __restrict__ ws,
    float* __restrict__ Q, float* __restrict__ Fh,
    float* __restrict__ Hh, float* __restrict__ Gh)
{
    const int c  = blockIdx.x * 64 + threadIdx.x;   // 0 .. NS*NH-1
    const int s  = c >> 4;
    const int nh = c & 15;

    // ---- per-head parameter transforms (once) ----
    float mx = -INFINITY;
    #pragma unroll
    for (int i = 0; i < NH; ++i) mx = fmaxf(mx, w_o[i]);
    float ssum = 0.f;
    #pragma unroll
    for (int i = 0; i < NH; ++i) ssum += expf(w_o[i] - mx);
    const float a = expf(w_o[nh] - mx) / ssum;

    const float melt  = expf(wF[nh]) + 1.0f;
    const float cap   = expf(2.0f * wl[nh]);
    const float swe   = 1.0f / (1.0f + expf(-we[nh]));
    const float swk   = 1.0f / (1.0f + expf(-wk[nh]));
    const float sws   = 1.0f / (1.0f + expf(-ws[nh]));
    const float swG   = 1.0f / (1.0f + expf(-wG[nh]));
    const float omsws = 1.0f - sws;

    float f = 0.0f, h = 0.0f, g = 0.0f;

    int li = s;                                   // load index into P/T/E
    const size_t ostride = (size_t)NS * NH;
    float* pf = Fh + (size_t)s * NH + nh;
    float* ph = Hh + (size_t)s * NH + nh;
    float* pg = Gh + (size_t)s * NH + nh;
    float* pq = Q + s;

    // prefetch first group
    float Pb[U], Tb[U], Eb[U];
    #pragma unroll
    for (int j = 0; j < U; ++j) {
        Pb[j] = P[li]; Tb[j] = T[li]; Eb[j] = E[li]; li += NS;
    }

    for (int t0 = 0; t0 < NT; t0 += U) {
        float Pc[U], Tc[U], Ec[U];
        #pragma unroll
        for (int j = 0; j < U; ++j) { Pc[j] = Pb[j]; Tc[j] = Tb[j]; Ec[j] = Eb[j]; }

        // issue next group's loads early (independent; overlap with compute)
        if (t0 + U < NT) {
            #pragma unroll
            for (int j = 0; j < U; ++j) {
                Pb[j] = P[li]; Tb[j] = T[li]; Eb[j] = E[li]; li += NS;
            }
        }

        float qs[U];
        #pragma unroll
        for (int j = 0; j < U; ++j) {
            const float Tk = Tc[j], Pk = Pc[j], Ek = Ec[j];
            // SnowBucket
            const float sm = fmaxf(Tk, 0.0f) * melt;
            const float m  = fminf(sm, f);
            f = f - m + (Tk < 0.0f ? Pk : 0.0f);
            const float x  = (Tk > 0.0f ? Pk : 0.0f) + m;
            // SoilBucket
            const float hn = h + x;
            const float h1 = fmaxf(hn - cap, 0.0f);
            const float q1 = fmaxf(h1 - Ek * swe, 0.0f);
            const float h2 = hn - h1;
            const float q2 = h2 * swk;
            h = h2 - q2;
            const float q2a = q2 * sws;
            const float q2b = q2 * omsws;
            // LinearBucket
            const float q3 = (q2b + g) * swG;
            g = g - q3 + q2b;
            qs[j] = (q1 + q2a + q3) * a;

            __builtin_nontemporal_store(f, pf); pf += ostride;
            __builtin_nontemporal_store(h, ph); ph += ostride;
            __builtin_nontemporal_store(g, pg); pg += ostride;
        }

        // 16-lane row sums via DPP prefix adds: lane nh==15 gets the total.
        // 16 independent chains -> the 4-deep DPP dependency overlaps freely.
        #pragma unroll
        for (int j = 0; j < U; ++j) {
            float v = qs[j];
            v = DPP_SHR_ADD(v, 0x111);   // row_shr:1
            v = DPP_SHR_ADD(v, 0x112);   // row_shr:2
            v = DPP_SHR_ADD(v, 0x114);   // row_shr:4
            v = DPP_SHR_ADD(v, 0x118);   // row_shr:8
            qs[j] = v;
        }
        if (nh == 15) {
            #pragma unroll
            for (int j = 0; j < U; ++j)
                __builtin_nontemporal_store(qs[j], pq + (size_t)(t0 + j) * NS);
        }
    }
}

extern "C" void kernel_launch(void* const* d_in, const int* in_sizes, int n_in,
                              void* d_out, int out_size, void* d_ws, size_t ws_size,
                              hipStream_t stream) {
    const float* P   = (const float*)d_in[0];
    const float* T   = (const float*)d_in[1];
    const float* E   = (const float*)d_in[2];
    const float* w_o = (const float*)d_in[3];
    const float* wF  = (const float*)d_in[4];
    const float* wG  = (const float*)d_in[5];
    const float* wl  = (const float*)d_in[6];
    const float* we  = (const float*)d_in[7];
    const float* wk  = (const float*)d_in[8];
    const float* ws  = (const float*)d_in[9];

    float* Q  = (float*)d_out;
    float* Fh = Q  + (size_t)NT * NS;
    float* Hh = Fh + (size_t)NT * NS * NH;
    float* Gh = Hh + (size_t)NT * NS * NH;

    const int threads = NS * NH;          // 32768 chains
    dim3 block(64);
    dim3 grid(threads / 64);              // 512 blocks -> 2 waves/CU
    waternet_kernel<<<grid, block, 0, stream>>>(P, T, E, w_o, wF, wG, wl, we, wk, ws,
                                                Q, Fh, Hh, Gh);
}